// Round 8
// baseline (112.675 us; speedup 1.0000x reference)
//
#include <hip/hip_runtime.h>

// out[t, j] = W[j, x[t]] + b[j]
//   x : [16384] int32, W : [1024, 50257] f32 row-major, b : [1024] f32
//   out: [16384, 1024] f32
//
// R2/R6 (sorted, 1 token/block): 124-128us, FETCH 102MB. R6 doubled
// per-wave in-flight loads (VGPR=16 proved it) with ZERO gain => bound by
// per-CU outstanding-miss slots (~120 MSHR @ ~550cyc => 0.22 trans/cyc/CU,
// 65.5K trans/CU = 124us). More issued loads just queue.
// R7: cut MISS COUNT ~5x. 4 consecutive sorted tokens per block, same
// per-thread j-set; issue the 4 token-loads per j ADJACENTLY (j-major) so
// same-line loads (sorted-adjacent tokens share 64B lines, ~5.2/line)
// merge in the MSHR as secondary misses -> 1 transaction per (line,block).
// sched_barrier(0) pins all 16 loads before uses (R5's sinking failure,
// fixed in R6). Grid 4096 XCD-chunked keeps cross-block sharers on the
// same L2.
// (Round 8 = resubmit of round 7: container died, no bench data.)

#define VOCAB 50257
#define DIM   1024
#define NBUCK ((VOCAB + 15) >> 4)     // 3142 line-groups
#define NXCD  8
#define TPB_TOK 4                     // tokens per block

// ---------- sort pipeline (counting sort by v>>4) ----------

__global__ void zero_counts_kernel(int* __restrict__ counts, int n) {
    int i = blockIdx.x * blockDim.x + threadIdx.x;
    if (i < n) counts[i] = 0;
}

__global__ void hist_kernel(const int* __restrict__ x, int n, int* __restrict__ counts) {
    int i = blockIdx.x * blockDim.x + threadIdx.x;
    if (i < n) atomicAdd(&counts[x[i] >> 4], 1);
}

// single block, 256 threads: exclusive prefix sum over NBUCK counters
__global__ __launch_bounds__(256) void scan_kernel(const int* __restrict__ counts,
                                                   int* __restrict__ offs) {
    const int CHUNK = (NBUCK + 255) / 256;   // 13
    __shared__ int lds[256];
    const int tid = threadIdx.x;
    const int base = tid * CHUNK;
    int local[CHUNK];
    int s = 0;
#pragma unroll
    for (int k = 0; k < CHUNK; ++k) {
        int idx = base + k;
        int c = (idx < NBUCK) ? counts[idx] : 0;
        local[k] = s;
        s += c;
    }
    lds[tid] = s;
    __syncthreads();
    if (tid == 0) {
        int run = 0;
        for (int i = 0; i < 256; ++i) { int c = lds[i]; lds[i] = run; run += c; }
    }
    __syncthreads();
    const int boff = lds[tid];
#pragma unroll
    for (int k = 0; k < CHUNK; ++k) {
        int idx = base + k;
        if (idx < NBUCK) offs[idx] = boff + local[k];
    }
}

// offs consumed as running cursors (recomputed every call). Intra-bucket
// order is nondeterministic but out[t] depends only on t's own v ->
// deterministic OUTPUT. Packs (v << 16) | t : v < 65536, t < 65536.
__global__ void scatter_kernel(const int* __restrict__ x, int n,
                               int* __restrict__ offs, int* __restrict__ order) {
    int i = blockIdx.x * blockDim.x + threadIdx.x;
    if (i < n) {
        int v = x[i];
        int pos = atomicAdd(&offs[v >> 4], 1);
        order[pos] = (v << 16) | i;
    }
}

// ---------- gather: 4 sorted tokens/block, j-major issue, MSHR-merge ----------
__global__ __launch_bounds__(256) void gather_t4_kernel(
    const float* __restrict__ W,
    const float* __restrict__ bias,
    const int* __restrict__ order,
    float* __restrict__ out,
    int n, int q, int r)   // q = nblk/8, r = nblk%8
{
    // bijective XCD chunking: round-robin hw blocks -> contiguous sorted ranges
    const int bid = blockIdx.x;
    const int xcd = bid & (NXCD - 1);
    const int idx = bid >> 3;
    const int chunk_base = (xcd < r) ? xcd * (q + 1) : r * (q + 1) + (xcd - r) * q;
    const int t0 = (chunk_base + idx) * TPB_TOK;
    const int cnt = min(TPB_TOK, n - t0);

    int pk[TPB_TOK];
#pragma unroll
    for (int k = 0; k < TPB_TOK; ++k)
        pk[k] = order[t0 + ((k < cnt) ? k : 0)];   // block-uniform -> scalar

    const int j0 = threadIdx.x * 4;

    // j-major: the 4 token-loads for one j are adjacent instructions, so
    // same-line requests (tokens in the same v>>4 group) MSHR-merge.
    float w[4][TPB_TOK];                 // fully unrolled -> registers
#pragma unroll
    for (int jj = 0; jj < 4; ++jj) {
        const float* row = W + (size_t)(j0 + jj) * VOCAB;
#pragma unroll
        for (int k = 0; k < TPB_TOK; ++k)
            w[jj][k] = row[((unsigned)pk[k]) >> 16];
    }
    __builtin_amdgcn_sched_barrier(0);   // keep all 16 loads issued before use

    const float4 bb = *reinterpret_cast<const float4*>(bias + j0);

#pragma unroll
    for (int k = 0; k < TPB_TOK; ++k) {
        if (k < cnt) {
            const int t = pk[k] & 0xFFFF;
            float4 o;
            o.x = w[0][k] + bb.x;
            o.y = w[1][k] + bb.y;
            o.z = w[2][k] + bb.z;
            o.w = w[3][k] + bb.w;
            *reinterpret_cast<float4*>(out + (size_t)t * DIM + j0) = o;
        }
    }
}

// fallback (round-1 kernel) if workspace too small / n too large for packing
__global__ __launch_bounds__(256) void gather_direct_kernel(
    const int* __restrict__ x,
    const float* __restrict__ W,
    const float* __restrict__ bias,
    float* __restrict__ out)
{
    const int t = blockIdx.x;
    const int v = x[t];
    const int j0 = threadIdx.x * 4;
    float4 rr;
    rr.x = W[(size_t)(j0 + 0) * VOCAB + v];
    rr.y = W[(size_t)(j0 + 1) * VOCAB + v];
    rr.z = W[(size_t)(j0 + 2) * VOCAB + v];
    rr.w = W[(size_t)(j0 + 3) * VOCAB + v];
    const float4 bb = *reinterpret_cast<const float4*>(bias + j0);
    rr.x += bb.x; rr.y += bb.y; rr.z += bb.z; rr.w += bb.w;
    *reinterpret_cast<float4*>(out + (size_t)t * DIM + j0) = rr;
}

extern "C" void kernel_launch(void* const* d_in, const int* in_sizes, int n_in,
                              void* d_out, int out_size, void* d_ws, size_t ws_size,
                              hipStream_t stream) {
    const int*   x    = (const int*)d_in[0];
    const float* W    = (const float*)d_in[1];
    const float* bias = (const float*)d_in[2];
    float*       out  = (float*)d_out;

    const int n = in_sizes[0];           // 16384 tokens

    const size_t need = (size_t)(2 * NBUCK + n) * sizeof(int);
    if (ws_size < need || n > 65536) {   // packing uses 16 bits for token id
        gather_direct_kernel<<<n, 256, 0, stream>>>(x, W, bias, out);
        return;
    }

    int* counts = (int*)d_ws;            // [NBUCK]
    int* offs   = counts + NBUCK;        // [NBUCK]
    int* order  = offs + NBUCK;          // [n] packed (v<<16 | t)

    const int tb = 256;
    zero_counts_kernel<<<(NBUCK + tb - 1) / tb, tb, 0, stream>>>(counts, NBUCK);
    hist_kernel<<<(n + tb - 1) / tb, tb, 0, stream>>>(x, n, counts);
    scan_kernel<<<1, tb, 0, stream>>>(counts, offs);
    scatter_kernel<<<(n + tb - 1) / tb, tb, 0, stream>>>(x, n, offs, order);

    const int nblk = (n + TPB_TOK - 1) / TPB_TOK;   // 4096
    const int q = nblk / NXCD, r = nblk % NXCD;
    gather_t4_kernel<<<nblk, 256, 0, stream>>>(W, bias, order, out, n, q, r);
}